// Round 3
// baseline (897.244 us; speedup 1.0000x reference)
//
#include <hip/hip_runtime.h>
#include <math.h>

#define L_TOT 36864
#define BN_EPS 1e-5f
#define PCH 45000   // padded channel stride: 18*50*50

typedef __attribute__((ext_vector_type(8))) short bf16x8;
typedef __attribute__((ext_vector_type(4))) float f32x4;

__device__ __forceinline__ float fsigmoid(float x){ return 1.f/(1.f+__expf(-x)); }
__device__ __forceinline__ float fsoftplus(float x){
  float e = __expf(x);
  return (x>20.f)? x : __logf(1.f+e);
}
__device__ __forceinline__ unsigned short f2bf(float x){
  union { float f; unsigned u; } cv; cv.f = x;
  unsigned r = (cv.u + 0x7FFFu + ((cv.u>>16)&1u)) >> 16;
  return (unsigned short)r;
}
__host__ __device__ constexpr int off3c(int r){
  return (r>=27) ? 0 : ((r/9)-1)*2500 + (((r%9)/3)-1)*50 + ((r%3)-1);
}

// ---- device-scope grid barrier (all blocks provably co-resident; see launch) ----
__device__ __forceinline__ void grid_barrier(unsigned* c, unsigned nblk){
  __syncthreads();                 // drains this block's global stores (vmcnt(0))
  if (threadIdx.x == 0){
    __hip_atomic_fetch_add(c, 1u, __ATOMIC_ACQ_REL, __HIP_MEMORY_SCOPE_AGENT);
    unsigned spins = 0;
    while (__hip_atomic_load(c, __ATOMIC_ACQUIRE, __HIP_MEMORY_SCOPE_AGENT) < nblk){
      __builtin_amdgcn_s_sleep(8);
      if (++spins > (1u<<26)) break;   // failsafe: clean fail instead of hang
    }
  }
  __syncthreads();
}

// ---------------- setup: pack conv weights + zero bf16 halo buffer/stats/barriers -
__global__ void k_setup(const float* __restrict__ w1, unsigned short* __restrict__ wA1,
                        const float* __restrict__ w2, unsigned short* __restrict__ wA2,
                        float* __restrict__ stats, unsigned* __restrict__ bar,
                        float* __restrict__ bfz) {
  int b = blockIdx.x, tid = threadIdx.x;
  int idx = b*256 + tid;
  if (idx < 16*PCH) bfz[idx] = 0.f;     // zero all 32 bf16 channels (as 32-bit words)
  if (b < 4){
    int k = b*256 + tid;
    if (k < 864){
      int ic = k & 31, r = k >> 5;
      for (int m=0;m<16;m++){
        float v = (r < 27) ? w1[m*32*27 + ic*27 + r] : 0.f;
        wA1[(((k>>3)*16) + m)*8 + (k&7)] = f2bf(v);
      }
    }
  } else if (b < 6){
    int k = (b-4)*256 + tid;
    if (k < 448){
      int ic = k & 15, r = k >> 4;
      for (int m=0;m<16;m++){
        float v = (r < 27) ? w2[m*16*27 + ic*27 + r] : 0.f;
        wA2[(((k>>3)*16) + m)*8 + (k&7)] = f2bf(v);
      }
    }
  } else if (b == 6){
    if (tid < 64) stats[tid] = 0.f;
    if (tid >= 64 && tid < 68) bar[tid-64] = 0u;   // re-zero barrier counters per iter
  }
}

struct MambaArgs {
  const float *x0, *x1, *bstats, *bg, *bbp;
  const float *lnw, *lnb, *inw, *cw, *cb, *xpw, *dtw, *dtb, *Alog, *Dp, *ow;
  const float *r0src, *r1src;
  float *aggA, *aggB, *carry;
  unsigned *bar0, *bar1;
  unsigned short* rp;
};

// =================================================================================
// k_mamba: ONE kernel for the whole mamba block (manual grid barrier, all 768
// blocks co-resident: LDS 48.2KB -> exactly 3 blocks/CU, VGPR capped by bounds).
//   front (LN/BN + in-proj + dwconv + x-proj + dt + pass1) -> barrier
//   -> carry scan (first NCB blocks)                        -> barrier
//   -> pass2 + z-gate (z in registers) + out-proj + residual -> bf16 padded.
// xc/dt/B/C stay in LDS across the barriers; z never touches memory.
// =================================================================================
template<int DIM, int DI, int DTR, bool DOBN, int RES>
__global__ __launch_bounds__(256,3) void k_mamba(MambaArgs a)
{
  constexpr int TCH  = 48;
  constexpr int NCHUNK = 768;
  constexpr int ROWS = DTR + 32;
  constexpr int NSH  = 256/DI;        // threads per d-channel in scan
  constexpr int SPB  = 16/NSH;        // states per thread
  constexpr int CH   = DI*16;         // channels per chunk in agg/carry
  constexpr int NCB  = CH/64;         // carry blocks
  constexpr int NZ   = DI/4;          // z values held per thread
  constexpr int R0SZ = DI*64;         // region0: SX (DIM*64) / xs+halo (DI*64) / dt (DI*49)
  constexpr int O_SXC = R0SZ;         // DI*49
  constexpr int O_SB  = O_SXC + DI*49;// 16*49
  constexpr int O_SC  = O_SB + 16*49; // 16*49
  constexpr int O_SY  = O_SC + 16*49; // DI*49  (also carry scratch 512)
  constexpr int O_DTP = O_SY + DI*49; // DTR*48
  constexpr int SMEM  = O_DTP + DTR*48 + 16;
  __shared__ float sm[SMEM];

  const int tid   = threadIdx.x;
  const int chunk = blockIdx.x;
  const int t0    = chunk*TCH;

  // ---- P0: load x (+optional BN-normalize) into region0; cols 0..50 = t0-3..t0+47
  for (int idx = tid; idx < DIM*64; idx += 256){
    int c = idx >> 6, i2 = idx & 63;
    int t = t0 - 3 + i2;
    float v = 0.f;
    if (i2 < 51 && t >= 0){
      if constexpr (DOBN){
        float raw = a.x0[c*L_TOT + t];
        float bm = a.bstats[2*c]*(1.f/L_TOT);
        float bv = a.bstats[2*c+1]*(1.f/L_TOT) - bm*bm;
        v = (raw - bm)*rsqrtf(bv+BN_EPS)*a.bg[c] + a.bbp[c];
      } else {
        v = (c < 16) ? a.x0[c*L_TOT + t] : a.x1[(c-16)*L_TOT + t];
      }
    }
    sm[idx] = v;
  }
  __syncthreads();

  // ---- P1: LayerNorm per column, in place
  if (tid < 64){
    float s = 0.f, s2 = 0.f;
#pragma unroll
    for (int c = 0; c < DIM; c++){
      float v = sm[c*64 + tid];
      s += v; s2 += v*v;
    }
    float m  = s*(1.f/DIM);
    float var = s2*(1.f/DIM) - m*m;
    float rs = rsqrtf(var + BN_EPS);
#pragma unroll
    for (int c = 0; c < DIM; c++){
      float v = sm[c*64 + tid];
      sm[c*64 + tid] = (v-m)*rs*a.lnw[c] + a.lnb[c];
    }
  }
  __syncthreads();

  // ---- P2: in-proj.  xs rows -> region0 (over SX), z rows -> registers
  const int i   = tid & 63;
  const int r0w = tid >> 6;
  float zreg[NZ];
  {
    float xn[DIM];
#pragma unroll
    for (int c = 0; c < DIM; c++) xn[c] = sm[c*64 + i];
    __syncthreads();                     // everyone finished reading SX
    int zi = 0;
    for (int r = r0w; r < 2*DI; r += 4){
      float acc = 0.f;
#pragma unroll
      for (int c = 0; c < DIM; c++) acc += xn[c]*a.inw[r*DIM + c];
      if (r < DI){
        if (i < 51) sm[r*64 + i] = (t0 == 0 && i < 3) ? 0.f : acc;
      } else {
        zreg[zi++] = acc;                // z for (row r-DI, col i) kept in regs
      }
    }
  }
  __syncthreads();

  // ---- P3: causal depthwise conv (kw=4) + SiLU -> SXC
  for (int idx = tid; idx < DI*48; idx += 256){
    int d = idx / 48, j = idx - d*48;
    const float* xr = &sm[d*64 + j];     // xr[k] = xs[t-3+k]
    float acc = a.cb[d] + a.cw[d*4+0]*xr[0] + a.cw[d*4+1]*xr[1]
                        + a.cw[d*4+2]*xr[2] + a.cw[d*4+3]*xr[3];
    sm[O_SXC + d*49 + j] = acc * fsigmoid(acc);
  }
  __syncthreads();

  // ---- P4: x-proj -> dtp | B | C
  {
    constexpr int NR = (ROWS + 3) / 4;
    float acc[NR];
#pragma unroll
    for (int rr = 0; rr < NR; rr++) acc[rr] = 0.f;
    for (int db = 0; db < DI; db += 16){
      float xcol[16];
#pragma unroll
      for (int k = 0; k < 16; k++) xcol[k] = sm[O_SXC + (db+k)*49 + i];
#pragma unroll
      for (int rr = 0; rr < NR; rr++){
        int r = r0w + rr*4;
        if (r < ROWS){
          float a2 = 0.f;
#pragma unroll
          for (int k = 0; k < 16; k++) a2 += xcol[k]*a.xpw[r*DI + db + k];
          acc[rr] += a2;
        }
      }
    }
    if (i < 48){
#pragma unroll
      for (int rr = 0; rr < NR; rr++){
        int r = r0w + rr*4;
        if (r < ROWS){
          if (r < DTR)          sm[O_DTP + r*48 + i] = acc[rr];
          else if (r < DTR+16)  sm[O_SB + (r-DTR)*49 + i] = acc[rr];
          else                  sm[O_SC + (r-DTR-16)*49 + i] = acc[rr];
        }
      }
    }
  }
  __syncthreads();

  // ---- P5: dt = softplus(dtb + dtw*dtp) -> region0 (xs dead)
  for (int idx = tid; idx < DI*48; idx += 256){
    int d = idx / 48, j = idx - d*48;
    float pre = a.dtb[d] + a.dtw[d*DTR]*sm[O_DTP + j];
    if (DTR > 1) pre += a.dtw[d*DTR + DTR-1]*sm[O_DTP + (DTR-1)*48 + j];
    sm[d*49 + j] = fsoftplus(pre);
  }
  __syncthreads();

  // ---- P6: pass1 scan -> per-chunk (A,B) aggregates in global
  const int dd = tid / NSH;
  const int sh = tid - dd*NSH;
  float Av[SPB];
#pragma unroll
  for (int j = 0; j < SPB; j++) Av[j] = -__expf(a.Alog[dd*16 + sh*SPB + j]);
  {
    float Ar[SPB], Br[SPB];
#pragma unroll
    for (int j = 0; j < SPB; j++){ Ar[j] = 1.f; Br[j] = 0.f; }
    for (int t = 0; t < TCH; t++){
      float dtv = sm[dd*49 + t];
      float bb2 = dtv * sm[O_SXC + dd*49 + t];
#pragma unroll
      for (int j = 0; j < SPB; j++){
        float a2 = __expf(dtv*Av[j]);
        Ar[j] *= a2;
        Br[j] = a2*Br[j] + bb2*sm[O_SB + (sh*SPB+j)*49 + t];
      }
    }
    const int o = chunk*CH + tid*SPB;
    if constexpr (SPB == 4){
      *reinterpret_cast<float4*>(&a.aggA[o]) = make_float4(Ar[0],Ar[1],Ar[2],Ar[3]);
      *reinterpret_cast<float4*>(&a.aggB[o]) = make_float4(Br[0],Br[1],Br[2],Br[3]);
    } else {
      *reinterpret_cast<float2*>(&a.aggA[o]) = make_float2(Ar[0],Ar[1]);
      *reinterpret_cast<float2*>(&a.aggB[o]) = make_float2(Br[0],Br[1]);
    }
  }
  grid_barrier(a.bar0, NCHUNK);

  // ---- carry scan over chunk aggregates (first NCB blocks; SY region as scratch)
  if (blockIdx.x < NCB){
    const int lane = tid & 63, seg = tid >> 6;
    const int ch = blockIdx.x*64 + lane;
    constexpr int SEG = NCHUNK/4;
    const int c0 = seg*SEG;
    float aa = 1.f, bb3 = 0.f;
    for (int cb = c0; cb < c0+SEG; cb += 8){
      float av[8], bv[8];
#pragma unroll
      for (int k=0;k<8;k++){ av[k]=a.aggA[(cb+k)*CH+ch]; bv[k]=a.aggB[(cb+k)*CH+ch]; }
#pragma unroll
      for (int k=0;k<8;k++){ aa = aa*av[k]; bb3 = av[k]*bb3 + bv[k]; }
    }
    float* sca = &sm[O_SY];
    float* scb = &sm[O_SY + 256];
    sca[seg*64+lane] = aa; scb[seg*64+lane] = bb3;
    __syncthreads();
    if (seg == 0){
      float pa = 1.f, pb = 0.f;
      for (int g = 0; g < 4; g++){
        float ca = sca[g*64+lane], cb2 = scb[g*64+lane];
        sca[g*64+lane] = pa; scb[g*64+lane] = pb;
        float na = pa*ca;
        float nb = ca*pb + cb2;
        pa = na; pb = nb;
      }
    }
    __syncthreads();
    float h = scb[seg*64+lane];
    for (int cb = c0; cb < c0+SEG; cb += 8){
      float av[8], bv[8];
#pragma unroll
      for (int k=0;k<8;k++){ av[k]=a.aggA[(cb+k)*CH+ch]; bv[k]=a.aggB[(cb+k)*CH+ch]; }
#pragma unroll
      for (int k=0;k<8;k++){ a.carry[(cb+k)*CH+ch] = h; h = av[k]*h + bv[k]; }
    }
  }
  grid_barrier(a.bar1, NCHUNK);

  // ---- pass2: h update + y = sum_s h*C + xc*D -> SY  (xc/dt/B/C still in LDS!)
  {
    float h[SPB];
    const int o = chunk*CH + tid*SPB;
    if constexpr (SPB == 4){
      float4 hv = *reinterpret_cast<const float4*>(&a.carry[o]);
      h[0]=hv.x; h[1]=hv.y; h[2]=hv.z; h[3]=hv.w;
    } else {
      float2 hv = *reinterpret_cast<const float2*>(&a.carry[o]);
      h[0]=hv.x; h[1]=hv.y;
    }
    const float Dv = a.Dp[dd];
    for (int t = 0; t < TCH; t++){
      float dtv = sm[dd*49 + t];
      float xcv = sm[O_SXC + dd*49 + t];
      float bb2 = dtv*xcv;
      float p = 0.f;
#pragma unroll
      for (int j = 0; j < SPB; j++){
        float a2 = __expf(dtv*Av[j]);
        h[j] = a2*h[j] + bb2*sm[O_SB + (sh*SPB+j)*49 + t];
        p += h[j]*sm[O_SC + (sh*SPB+j)*49 + t];
      }
#pragma unroll
      for (int o2 = 1; o2 < NSH; o2 <<= 1) p += __shfl_xor(p, o2);
      if (sh == 0) sm[O_SY + dd*49 + t] = p + xcv*Dv;
    }
  }
  __syncthreads();

  // ---- gate: y *= silu(z), z from registers (thread holds rows r0w+4u, col i)
  if (i >= 3 && i < 51){
#pragma unroll
    for (int u = 0; u < NZ; u++){
      float zv = zreg[u];
      sm[O_SY + (r0w + 4*u)*49 + (i-3)] *= zv*fsigmoid(zv);
    }
  }
  __syncthreads();

  // ---- out-proj + residual -> padded bf16 conv input
  {
    constexpr int NO = DIM/4;
    float acc[NO];
#pragma unroll
    for (int rr = 0; rr < NO; rr++) acc[rr] = 0.f;
    for (int db = 0; db < DI; db += 16){
      float ycol[16];
#pragma unroll
      for (int k = 0; k < 16; k++) ycol[k] = sm[O_SY + (db+k)*49 + i];
#pragma unroll
      for (int rr = 0; rr < NO; rr++){
        int r = r0w + rr*4;
        float a2 = 0.f;
#pragma unroll
        for (int k = 0; k < 16; k++) a2 += ycol[k]*a.ow[r*DI + db + k];
        acc[rr] += a2;
      }
    }
    if (i < 48){
      const int t  = t0 + i;
      const int zz = chunk / 48, yy = chunk - zz*48;
      const int pb2 = (zz+1)*2500 + (yy+1)*50 + (i+1);
#pragma unroll
      for (int rr = 0; rr < NO; rr++){
        int r = r0w + rr*4;
        float res;
        if (RES == 0){
          res = (r < 16) ? a.r0src[r*L_TOT + t] : a.r1src[(r-16)*L_TOT + t];
        } else {
          float bm = a.bstats[2*r]*(1.f/L_TOT);
          float bv = a.bstats[2*r+1]*(1.f/L_TOT) - bm*bm;
          res = (a.r0src[r*L_TOT + t] - bm)*rsqrtf(bv+BN_EPS)*a.bg[r] + a.bbp[r];
        }
        a.rp[r*PCH + pb2] = f2bf(acc[rr] + res);
      }
    }
  }
}

// ---------------- conv3d via MFMA implicit GEMM + fused BN partial sums -----------
template<int IC>
__global__ __launch_bounds__(256) void k_conv_mfma(const unsigned short* __restrict__ bin,
                         const unsigned short* __restrict__ wA,
                         const float* __restrict__ bias, float* __restrict__ out,
                         float* __restrict__ stats) {
  constexpr int NKB = (IC==32) ? 27 : 14;
  __shared__ float sred[32];
  if (threadIdx.x < 32) sred[threadIdx.x] = 0.f;
  __syncthreads();
  const int lane = threadIdx.x & 63;
  const int n = lane & 15, quad = lane >> 4;
  const int tile = blockIdx.x*4 + (threadIdx.x >> 6);
  const int t = tile*16 + n;
  int zz = t / 2304;
  int r2 = t - zz*2304;
  int yy = r2 / 48;
  int xx = r2 - yy*48;
  int pb = (zz+1)*2500 + (yy+1)*50 + (xx+1);
  const unsigned short* bp[8];
#pragma unroll
  for (int j=0;j<8;j++){
    int e = quad*8 + j;
    int ic = (IC==32) ? e : (e & 15);
    bp[j] = bin + ic*PCH + pb;
  }
  const int rq = (IC==32) ? 0 : (quad >> 1);
  f32x4 acc = {0.f, 0.f, 0.f, 0.f};
#pragma unroll
  for (int kb=0; kb<NKB; kb++){
    bf16x8 af = *reinterpret_cast<const bf16x8*>(wA + (size_t)((kb*4+quad)*16 + n)*8);
    int off;
    if (IC==32) off = off3c(kb);
    else        off = rq ? off3c(2*kb+1) : off3c(2*kb);
    bf16x8 bf;
#pragma unroll
    for (int j=0;j<8;j++) bf[j] = (short)bp[j][off];
    acc = __builtin_amdgcn_mfma_f32_16x16x32_bf16(af, bf, acc, 0, 0, 0);
  }
  float vs[4];
#pragma unroll
  for (int reg=0; reg<4; reg++){
    int m = quad*4 + reg;
    float v = acc[reg] + bias[m];
    out[m*L_TOT + t] = v;
    vs[reg] = v;
  }
#pragma unroll
  for (int reg=0; reg<4; reg++){
    float a = vs[reg], b2 = vs[reg]*vs[reg];
#pragma unroll
    for (int o=1; o<16; o<<=1){ a += __shfl_xor(a,o); b2 += __shfl_xor(b2,o); }
    if (n == 0){
      atomicAdd(&sred[quad*4+reg], a);
      atomicAdd(&sred[16 + quad*4+reg], b2);
    }
  }
  __syncthreads();
  if (threadIdx.x < 16){
    atomicAdd(&stats[2*threadIdx.x],   sred[threadIdx.x]);
    atomicAdd(&stats[2*threadIdx.x+1], sred[16+threadIdx.x]);
  }
}

// ---------------- BN normalize, float4 --------------------------------------------
__global__ void k_bn_norm4(const float* __restrict__ raw, const float* __restrict__ stats,
                           const float* __restrict__ g, const float* __restrict__ b,
                           float* __restrict__ out) {
  int i = blockIdx.x*256 + threadIdx.x;         // over 16*L_TOT/4
  int c = i / (L_TOT/4);
  int tq = i - c*(L_TOT/4);
  float m = stats[2*c]*(1.f/L_TOT);
  float v = stats[2*c+1]*(1.f/L_TOT) - m*m;
  float sc = rsqrtf(v+BN_EPS)*g[c];
  float bs = b[c] - m*sc;
  float4 x = *reinterpret_cast<const float4*>(raw + c*L_TOT + tq*4);
  float4 o = make_float4(x.x*sc+bs, x.y*sc+bs, x.z*sc+bs, x.w*sc+bs);
  *reinterpret_cast<float4*>(out + c*L_TOT + tq*4) = o;
}

// =================================================================================
extern "C" void kernel_launch(void* const* d_in, const int* in_sizes, int n_in,
                              void* d_out, int out_size, void* d_ws, size_t ws_size,
                              hipStream_t stream) {
  const float* l        = (const float*)d_in[0];
  const float* s        = (const float*)d_in[1];
  const float* m1_ln_w  = (const float*)d_in[2];
  const float* m1_ln_b  = (const float*)d_in[3];
  const float* m1_in_w  = (const float*)d_in[4];
  const float* m1_cw    = (const float*)d_in[5];
  const float* m1_cb    = (const float*)d_in[6];
  const float* m1_xp_w  = (const float*)d_in[7];
  const float* m1_dt_w  = (const float*)d_in[8];
  const float* m1_dt_b  = (const float*)d_in[9];
  const float* m1_Alog  = (const float*)d_in[10];
  const float* m1_D     = (const float*)d_in[11];
  const float* m1_out_w = (const float*)d_in[12];
  const float* m2_ln_w  = (const float*)d_in[13];
  const float* m2_ln_b  = (const float*)d_in[14];
  const float* m2_in_w  = (const float*)d_in[15];
  const float* m2_cw    = (const float*)d_in[16];
  const float* m2_cb    = (const float*)d_in[17];
  const float* m2_xp_w  = (const float*)d_in[18];
  const float* m2_dt_w  = (const float*)d_in[19];
  const float* m2_dt_b  = (const float*)d_in[20];
  const float* m2_Alog  = (const float*)d_in[21];
  const float* m2_D     = (const float*)d_in[22];
  const float* m2_out_w = (const float*)d_in[23];
  const float* c1_w     = (const float*)d_in[24];
  const float* c1_b     = (const float*)d_in[25];
  const float* bn1_g    = (const float*)d_in[26];
  const float* bn1_b    = (const float*)d_in[27];
  const float* c2_w     = (const float*)d_in[28];
  const float* c2_b     = (const float*)d_in[29];
  const float* bn2_g    = (const float*)d_in[30];
  const float* bn2_b    = (const float*)d_in[31];

  float* ws = (float*)d_ws;
  const size_t L = L_TOT;
  float* conv1raw = ws;                  // 16L
  float* conv2raw = ws + 16*L;           // 16L
  float* aggA     = ws + 32*L;           // 786432
  float* aggB     = aggA + 786432;
  float* carry    = aggB + 786432;
  float* stats1   = carry + 786432;      // 32
  float* stats2   = stats1 + 32;         // 32
  unsigned* bar   = (unsigned*)(stats2 + 32);             // 4 barrier counters
  unsigned short* bfin = (unsigned short*)(stats2 + 48);  // 32ch * PCH bf16
  unsigned short* wA1  = bfin + 32*PCH;  // 13824 ushorts
  unsigned short* wA2  = wA1 + 13824;    // 7168 ushorts

  // setup: weight pack + zero bfin halo buffer + zero stats + zero barrier counters
  k_setup<<<2813,256,0,stream>>>(c1_w, wA1, c2_w, wA2, stats1, bar, (float*)bfin);

  // ================= stage 1: mamba(dim=32, di=64) persistent + conv1 ============
  MambaArgs a1 = { l, s, stats1, bn1_g, bn1_b,
                   m1_ln_w, m1_ln_b, m1_in_w, m1_cw, m1_cb, m1_xp_w,
                   m1_dt_w, m1_dt_b, m1_Alog, m1_D, m1_out_w,
                   l, s, aggA, aggB, carry, bar+0, bar+1, bfin };
  k_mamba<32,64,2,false,0><<<768,256,0,stream>>>(a1);
  k_conv_mfma<32><<<576,256,0,stream>>>(bfin, wA1, c1_b, conv1raw, stats1);

  // ================= stage 2: mamba(dim=16, di=32) persistent + conv2 ============
  MambaArgs a2 = { conv1raw, conv1raw, stats1, bn1_g, bn1_b,
                   m2_ln_w, m2_ln_b, m2_in_w, m2_cw, m2_cb, m2_xp_w,
                   m2_dt_w, m2_dt_b, m2_Alog, m2_D, m2_out_w,
                   conv1raw, conv1raw, aggA, aggB, carry, bar+2, bar+3, bfin };
  k_mamba<16,32,1,true,1><<<768,256,0,stream>>>(a2);
  k_conv_mfma<16><<<576,256,0,stream>>>(bfin, wA2, c2_b, conv2raw, stats2);
  k_bn_norm4<<<576,256,0,stream>>>(conv2raw, stats2, bn2_g, bn2_b, (float*)d_out);
}

// Round 4
// 457.237 us; speedup vs baseline: 1.9623x; 1.9623x over previous
//
#include <hip/hip_runtime.h>
#include <math.h>

#define L_TOT 36864
#define BN_EPS 1e-5f
#define PCH 45000   // padded channel stride: 18*50*50

typedef __attribute__((ext_vector_type(8))) short bf16x8;
typedef __attribute__((ext_vector_type(4))) float f32x4;

__device__ __forceinline__ float fsigmoid(float x){ return 1.f/(1.f+__expf(-x)); }
__device__ __forceinline__ float fsoftplus(float x){
  float e = __expf(x);
  return (x>20.f)? x : __logf(1.f+e);
}
__device__ __forceinline__ unsigned short f2bf(float x){
  union { float f; unsigned u; } cv; cv.f = x;
  unsigned r = (cv.u + 0x7FFFu + ((cv.u>>16)&1u)) >> 16;
  return (unsigned short)r;
}
__host__ __device__ constexpr int off3c(int r){
  return (r>=27) ? 0 : ((r/9)-1)*2500 + (((r%9)/3)-1)*50 + ((r%3)-1);
}

// ---- split grid barrier: release-signal / relaxed-poll + single acquire ----------
// RELAXED agent-scope polls bypass L2 (sc1) without invalidating caches; the one
// ACQUIRE after loop exit provides the invalidate that makes data reads fresh.
__device__ __forceinline__ void bar_signal(unsigned* c){
  __syncthreads();   // all threads' global stores drained (vmcnt0) before release
  if (threadIdx.x == 0)
    __hip_atomic_fetch_add(c, 1u, __ATOMIC_RELEASE, __HIP_MEMORY_SCOPE_AGENT);
}
__device__ __forceinline__ void bar_wait(unsigned* c, unsigned target){
  if (threadIdx.x == 0){
    unsigned spins = 0;
    while (__hip_atomic_load(c, __ATOMIC_RELAXED, __HIP_MEMORY_SCOPE_AGENT) < target){
      __builtin_amdgcn_s_sleep(4);
      if (++spins > (1u<<26)) break;   // failsafe: clean fail instead of hang
    }
    (void)__hip_atomic_load(c, __ATOMIC_ACQUIRE, __HIP_MEMORY_SCOPE_AGENT);
  }
  __syncthreads();
}

// ---------------- setup: pack conv weights + zero bf16 halo buffer/stats/barriers -
__global__ void k_setup(const float* __restrict__ w1, unsigned short* __restrict__ wA1,
                        const float* __restrict__ w2, unsigned short* __restrict__ wA2,
                        float* __restrict__ stats, unsigned* __restrict__ bar,
                        float* __restrict__ bfz) {
  int b = blockIdx.x, tid = threadIdx.x;
  int idx = b*256 + tid;
  if (idx < 16*PCH) bfz[idx] = 0.f;     // zero all 32 bf16 channels (as 32-bit words)
  if (b < 4){
    int k = b*256 + tid;
    if (k < 864){
      int ic = k & 31, r = k >> 5;
      for (int m=0;m<16;m++){
        float v = (r < 27) ? w1[m*32*27 + ic*27 + r] : 0.f;
        wA1[(((k>>3)*16) + m)*8 + (k&7)] = f2bf(v);
      }
    }
  } else if (b < 6){
    int k = (b-4)*256 + tid;
    if (k < 448){
      int ic = k & 15, r = k >> 4;
      for (int m=0;m<16;m++){
        float v = (r < 27) ? w2[m*16*27 + ic*27 + r] : 0.f;
        wA2[(((k>>3)*16) + m)*8 + (k&7)] = f2bf(v);
      }
    }
  } else if (b == 6){
    if (tid < 64) stats[tid] = 0.f;
    if (tid >= 64 && tid < 68) bar[tid-64] = 0u;   // re-zero barrier counters per iter
  }
}

struct MambaArgs {
  const float *x0, *x1, *bstats, *bg, *bbp;
  const float *lnw, *lnb, *inw, *cw, *cb, *xpw, *dtw, *dtb, *Alog, *Dp, *ow;
  const float *r0src, *r1src;
  float *aggA, *aggB, *carry;
  unsigned *bar0, *bar1;
  unsigned short* rp;
};

// =================================================================================
// k_mamba: ONE kernel for the whole mamba block (manual grid barrier, all 768
// blocks co-resident: LDS 48.2KB -> exactly 3 blocks/CU, VGPR capped by bounds).
//   front (LN/BN + in-proj + dwconv + x-proj + dt + pass1) -> signal bar0
//   -> carry blocks wait bar0, scan, signal bar1; others skip straight to bar1
//   -> pass2 + z-gate (z in registers) + out-proj + residual -> bf16 padded.
// xc/dt/B/C stay in LDS across the barriers; z never touches memory.
// =================================================================================
template<int DIM, int DI, int DTR, bool DOBN, int RES>
__global__ __launch_bounds__(256,3) void k_mamba(MambaArgs a)
{
  constexpr int TCH  = 48;
  constexpr int NCHUNK = 768;
  constexpr int ROWS = DTR + 32;
  constexpr int NSH  = 256/DI;        // threads per d-channel in scan
  constexpr int SPB  = 16/NSH;        // states per thread
  constexpr int CH   = DI*16;         // channels per chunk in agg/carry
  constexpr int NCB  = CH/64;         // carry blocks
  constexpr int NZ   = DI/4;          // z values held per thread
  constexpr int R0SZ = DI*64;         // region0: SX (DIM*64) / xs+halo (DI*64) / dt (DI*49)
  constexpr int O_SXC = R0SZ;         // DI*49
  constexpr int O_SB  = O_SXC + DI*49;// 16*49
  constexpr int O_SC  = O_SB + 16*49; // 16*49
  constexpr int O_SY  = O_SC + 16*49; // DI*49  (also carry scratch 512)
  constexpr int O_DTP = O_SY + DI*49; // DTR*48
  constexpr int SMEM  = O_DTP + DTR*48 + 16;
  __shared__ float sm[SMEM];

  const int tid   = threadIdx.x;
  const int chunk = blockIdx.x;
  const int t0    = chunk*TCH;

  // ---- P0: load x (+optional BN-normalize) into region0; cols 0..50 = t0-3..t0+47
  for (int idx = tid; idx < DIM*64; idx += 256){
    int c = idx >> 6, i2 = idx & 63;
    int t = t0 - 3 + i2;
    float v = 0.f;
    if (i2 < 51 && t >= 0){
      if constexpr (DOBN){
        float raw = a.x0[c*L_TOT + t];
        float bm = a.bstats[2*c]*(1.f/L_TOT);
        float bv = a.bstats[2*c+1]*(1.f/L_TOT) - bm*bm;
        v = (raw - bm)*rsqrtf(bv+BN_EPS)*a.bg[c] + a.bbp[c];
      } else {
        v = (c < 16) ? a.x0[c*L_TOT + t] : a.x1[(c-16)*L_TOT + t];
      }
    }
    sm[idx] = v;
  }
  __syncthreads();

  // ---- P1: LayerNorm per column, in place
  if (tid < 64){
    float s = 0.f, s2 = 0.f;
#pragma unroll
    for (int c = 0; c < DIM; c++){
      float v = sm[c*64 + tid];
      s += v; s2 += v*v;
    }
    float m  = s*(1.f/DIM);
    float var = s2*(1.f/DIM) - m*m;
    float rs = rsqrtf(var + BN_EPS);
#pragma unroll
    for (int c = 0; c < DIM; c++){
      float v = sm[c*64 + tid];
      sm[c*64 + tid] = (v-m)*rs*a.lnw[c] + a.lnb[c];
    }
  }
  __syncthreads();

  // ---- P2: in-proj.  xs rows -> region0 (over SX), z rows -> registers
  const int i   = tid & 63;
  const int r0w = tid >> 6;
  float zreg[NZ];
  {
    float xn[DIM];
#pragma unroll
    for (int c = 0; c < DIM; c++) xn[c] = sm[c*64 + i];
    __syncthreads();                     // everyone finished reading SX
    int zi = 0;
    for (int r = r0w; r < 2*DI; r += 4){
      float acc = 0.f;
#pragma unroll
      for (int c = 0; c < DIM; c++) acc += xn[c]*a.inw[r*DIM + c];
      if (r < DI){
        if (i < 51) sm[r*64 + i] = (t0 == 0 && i < 3) ? 0.f : acc;
      } else {
        zreg[zi++] = acc;                // z for (row r-DI, col i) kept in regs
      }
    }
  }
  __syncthreads();

  // ---- P3: causal depthwise conv (kw=4) + SiLU -> SXC
  for (int idx = tid; idx < DI*48; idx += 256){
    int d = idx / 48, j = idx - d*48;
    const float* xr = &sm[d*64 + j];     // xr[k] = xs[t-3+k]
    float acc = a.cb[d] + a.cw[d*4+0]*xr[0] + a.cw[d*4+1]*xr[1]
                        + a.cw[d*4+2]*xr[2] + a.cw[d*4+3]*xr[3];
    sm[O_SXC + d*49 + j] = acc * fsigmoid(acc);
  }
  __syncthreads();

  // ---- P4: x-proj -> dtp | B | C
  {
    constexpr int NR = (ROWS + 3) / 4;
    float acc[NR];
#pragma unroll
    for (int rr = 0; rr < NR; rr++) acc[rr] = 0.f;
    for (int db = 0; db < DI; db += 16){
      float xcol[16];
#pragma unroll
      for (int k = 0; k < 16; k++) xcol[k] = sm[O_SXC + (db+k)*49 + i];
#pragma unroll
      for (int rr = 0; rr < NR; rr++){
        int r = r0w + rr*4;
        if (r < ROWS){
          float a2 = 0.f;
#pragma unroll
          for (int k = 0; k < 16; k++) a2 += xcol[k]*a.xpw[r*DI + db + k];
          acc[rr] += a2;
        }
      }
    }
    if (i < 48){
#pragma unroll
      for (int rr = 0; rr < NR; rr++){
        int r = r0w + rr*4;
        if (r < ROWS){
          if (r < DTR)          sm[O_DTP + r*48 + i] = acc[rr];
          else if (r < DTR+16)  sm[O_SB + (r-DTR)*49 + i] = acc[rr];
          else                  sm[O_SC + (r-DTR-16)*49 + i] = acc[rr];
        }
      }
    }
  }
  __syncthreads();

  // ---- P5: dt = softplus(dtb + dtw*dtp) -> region0 (xs dead)
  for (int idx = tid; idx < DI*48; idx += 256){
    int d = idx / 48, j = idx - d*48;
    float pre = a.dtb[d] + a.dtw[d*DTR]*sm[O_DTP + j];
    if (DTR > 1) pre += a.dtw[d*DTR + DTR-1]*sm[O_DTP + (DTR-1)*48 + j];
    sm[d*49 + j] = fsoftplus(pre);
  }
  __syncthreads();

  // ---- P6: pass1 scan -> per-chunk (A,B) aggregates in global
  const int dd = tid / NSH;
  const int sh = tid - dd*NSH;
  float Av[SPB];
#pragma unroll
  for (int j = 0; j < SPB; j++) Av[j] = -__expf(a.Alog[dd*16 + sh*SPB + j]);
  {
    float Ar[SPB], Br[SPB];
#pragma unroll
    for (int j = 0; j < SPB; j++){ Ar[j] = 1.f; Br[j] = 0.f; }
    for (int t = 0; t < TCH; t++){
      float dtv = sm[dd*49 + t];
      float bb2 = dtv * sm[O_SXC + dd*49 + t];
#pragma unroll
      for (int j = 0; j < SPB; j++){
        float a2 = __expf(dtv*Av[j]);
        Ar[j] *= a2;
        Br[j] = a2*Br[j] + bb2*sm[O_SB + (sh*SPB+j)*49 + t];
      }
    }
    const int o = chunk*CH + tid*SPB;
    if constexpr (SPB == 4){
      *reinterpret_cast<float4*>(&a.aggA[o]) = make_float4(Ar[0],Ar[1],Ar[2],Ar[3]);
      *reinterpret_cast<float4*>(&a.aggB[o]) = make_float4(Br[0],Br[1],Br[2],Br[3]);
    } else {
      *reinterpret_cast<float2*>(&a.aggA[o]) = make_float2(Ar[0],Ar[1]);
      *reinterpret_cast<float2*>(&a.aggB[o]) = make_float2(Br[0],Br[1]);
    }
  }
  bar_signal(a.bar0);                       // publish aggA/aggB

  // ---- carry scan over chunk aggregates (first NCB blocks; SY region as scratch)
  if (blockIdx.x < NCB){
    bar_wait(a.bar0, NCHUNK);               // only carry blocks rendezvous on bar0
    const int lane = tid & 63, seg = tid >> 6;
    const int ch = blockIdx.x*64 + lane;
    constexpr int SEG = NCHUNK/4;
    const int c0 = seg*SEG;
    float aa = 1.f, bb3 = 0.f;
    for (int cb = c0; cb < c0+SEG; cb += 8){
      float av[8], bv[8];
#pragma unroll
      for (int k=0;k<8;k++){ av[k]=a.aggA[(cb+k)*CH+ch]; bv[k]=a.aggB[(cb+k)*CH+ch]; }
#pragma unroll
      for (int k=0;k<8;k++){ aa = aa*av[k]; bb3 = av[k]*bb3 + bv[k]; }
    }
    float* sca = &sm[O_SY];
    float* scb = &sm[O_SY + 256];
    sca[seg*64+lane] = aa; scb[seg*64+lane] = bb3;
    __syncthreads();
    if (seg == 0){
      float pa = 1.f, pb = 0.f;
      for (int g = 0; g < 4; g++){
        float ca = sca[g*64+lane], cb2 = scb[g*64+lane];
        sca[g*64+lane] = pa; scb[g*64+lane] = pb;
        float na = pa*ca;
        float nb = ca*pb + cb2;
        pa = na; pb = nb;
      }
    }
    __syncthreads();
    float h = scb[seg*64+lane];
    for (int cb = c0; cb < c0+SEG; cb += 8){
      float av[8], bv[8];
#pragma unroll
      for (int k=0;k<8;k++){ av[k]=a.aggA[(cb+k)*CH+ch]; bv[k]=a.aggB[(cb+k)*CH+ch]; }
#pragma unroll
      for (int k=0;k<8;k++){ a.carry[(cb+k)*CH+ch] = h; h = av[k]*h + bv[k]; }
    }
    bar_signal(a.bar1);                     // publish carry[]
  }
  bar_wait(a.bar1, NCB);                    // everyone waits for carries only

  // ---- pass2: h update + y = sum_s h*C + xc*D -> SY  (xc/dt/B/C still in LDS!)
  {
    float h[SPB];
    const int o = chunk*CH + tid*SPB;
    if constexpr (SPB == 4){
      float4 hv = *reinterpret_cast<const float4*>(&a.carry[o]);
      h[0]=hv.x; h[1]=hv.y; h[2]=hv.z; h[3]=hv.w;
    } else {
      float2 hv = *reinterpret_cast<const float2*>(&a.carry[o]);
      h[0]=hv.x; h[1]=hv.y;
    }
    const float Dv = a.Dp[dd];
    for (int t = 0; t < TCH; t++){
      float dtv = sm[dd*49 + t];
      float xcv = sm[O_SXC + dd*49 + t];
      float bb2 = dtv*xcv;
      float p = 0.f;
#pragma unroll
      for (int j = 0; j < SPB; j++){
        float a2 = __expf(dtv*Av[j]);
        h[j] = a2*h[j] + bb2*sm[O_SB + (sh*SPB+j)*49 + t];
        p += h[j]*sm[O_SC + (sh*SPB+j)*49 + t];
      }
#pragma unroll
      for (int o2 = 1; o2 < NSH; o2 <<= 1) p += __shfl_xor(p, o2);
      if (sh == 0) sm[O_SY + dd*49 + t] = p + xcv*Dv;
    }
  }
  __syncthreads();

  // ---- gate: y *= silu(z), z from registers (thread holds rows r0w+4u, col i)
  if (i >= 3 && i < 51){
#pragma unroll
    for (int u = 0; u < NZ; u++){
      float zv = zreg[u];
      sm[O_SY + (r0w + 4*u)*49 + (i-3)] *= zv*fsigmoid(zv);
    }
  }
  __syncthreads();

  // ---- out-proj + residual -> padded bf16 conv input
  {
    constexpr int NO = DIM/4;
    float acc[NO];
#pragma unroll
    for (int rr = 0; rr < NO; rr++) acc[rr] = 0.f;
    for (int db = 0; db < DI; db += 16){
      float ycol[16];
#pragma unroll
      for (int k = 0; k < 16; k++) ycol[k] = sm[O_SY + (db+k)*49 + i];
#pragma unroll
      for (int rr = 0; rr < NO; rr++){
        int r = r0w + rr*4;
        float a2 = 0.f;
#pragma unroll
        for (int k = 0; k < 16; k++) a2 += ycol[k]*a.ow[r*DI + db + k];
        acc[rr] += a2;
      }
    }
    if (i < 48){
      const int t  = t0 + i;
      const int zz = chunk / 48, yy = chunk - zz*48;
      const int pb2 = (zz+1)*2500 + (yy+1)*50 + (i+1);
#pragma unroll
      for (int rr = 0; rr < NO; rr++){
        int r = r0w + rr*4;
        float res;
        if (RES == 0){
          res = (r < 16) ? a.r0src[r*L_TOT + t] : a.r1src[(r-16)*L_TOT + t];
        } else {
          float bm = a.bstats[2*r]*(1.f/L_TOT);
          float bv = a.bstats[2*r+1]*(1.f/L_TOT) - bm*bm;
          res = (a.r0src[r*L_TOT + t] - bm)*rsqrtf(bv+BN_EPS)*a.bg[r] + a.bbp[r];
        }
        a.rp[r*PCH + pb2] = f2bf(acc[rr] + res);
      }
    }
  }
}

// ---------------- conv3d via MFMA implicit GEMM + fused BN partial sums -----------
template<int IC>
__global__ __launch_bounds__(256) void k_conv_mfma(const unsigned short* __restrict__ bin,
                         const unsigned short* __restrict__ wA,
                         const float* __restrict__ bias, float* __restrict__ out,
                         float* __restrict__ stats) {
  constexpr int NKB = (IC==32) ? 27 : 14;
  __shared__ float sred[32];
  if (threadIdx.x < 32) sred[threadIdx.x] = 0.f;
  __syncthreads();
  const int lane = threadIdx.x & 63;
  const int n = lane & 15, quad = lane >> 4;
  const int tile = blockIdx.x*4 + (threadIdx.x >> 6);
  const int t = tile*16 + n;
  int zz = t / 2304;
  int r2 = t - zz*2304;
  int yy = r2 / 48;
  int xx = r2 - yy*48;
  int pb = (zz+1)*2500 + (yy+1)*50 + (xx+1);
  const unsigned short* bp[8];
#pragma unroll
  for (int j=0;j<8;j++){
    int e = quad*8 + j;
    int ic = (IC==32) ? e : (e & 15);
    bp[j] = bin + ic*PCH + pb;
  }
  const int rq = (IC==32) ? 0 : (quad >> 1);
  f32x4 acc = {0.f, 0.f, 0.f, 0.f};
#pragma unroll
  for (int kb=0; kb<NKB; kb++){
    bf16x8 af = *reinterpret_cast<const bf16x8*>(wA + (size_t)((kb*4+quad)*16 + n)*8);
    int off;
    if (IC==32) off = off3c(kb);
    else        off = rq ? off3c(2*kb+1) : off3c(2*kb);
    bf16x8 bf;
#pragma unroll
    for (int j=0;j<8;j++) bf[j] = (short)bp[j][off];
    acc = __builtin_amdgcn_mfma_f32_16x16x32_bf16(af, bf, acc, 0, 0, 0);
  }
  float vs[4];
#pragma unroll
  for (int reg=0; reg<4; reg++){
    int m = quad*4 + reg;
    float v = acc[reg] + bias[m];
    out[m*L_TOT + t] = v;
    vs[reg] = v;
  }
#pragma unroll
  for (int reg=0; reg<4; reg++){
    float a = vs[reg], b2 = vs[reg]*vs[reg];
#pragma unroll
    for (int o=1; o<16; o<<=1){ a += __shfl_xor(a,o); b2 += __shfl_xor(b2,o); }
    if (n == 0){
      atomicAdd(&sred[quad*4+reg], a);
      atomicAdd(&sred[16 + quad*4+reg], b2);
    }
  }
  __syncthreads();
  if (threadIdx.x < 16){
    atomicAdd(&stats[2*threadIdx.x],   sred[threadIdx.x]);
    atomicAdd(&stats[2*threadIdx.x+1], sred[16+threadIdx.x]);
  }
}

// ---------------- BN normalize, float4 --------------------------------------------
__global__ void k_bn_norm4(const float* __restrict__ raw, const float* __restrict__ stats,
                           const float* __restrict__ g, const float* __restrict__ b,
                           float* __restrict__ out) {
  int i = blockIdx.x*256 + threadIdx.x;         // over 16*L_TOT/4
  int c = i / (L_TOT/4);
  int tq = i - c*(L_TOT/4);
  float m = stats[2*c]*(1.f/L_TOT);
  float v = stats[2*c+1]*(1.f/L_TOT) - m*m;
  float sc = rsqrtf(v+BN_EPS)*g[c];
  float bs = b[c] - m*sc;
  float4 x = *reinterpret_cast<const float4*>(raw + c*L_TOT + tq*4);
  float4 o = make_float4(x.x*sc+bs, x.y*sc+bs, x.z*sc+bs, x.w*sc+bs);
  *reinterpret_cast<float4*>(out + c*L_TOT + tq*4) = o;
}

// =================================================================================
extern "C" void kernel_launch(void* const* d_in, const int* in_sizes, int n_in,
                              void* d_out, int out_size, void* d_ws, size_t ws_size,
                              hipStream_t stream) {
  const float* l        = (const float*)d_in[0];
  const float* s        = (const float*)d_in[1];
  const float* m1_ln_w  = (const float*)d_in[2];
  const float* m1_ln_b  = (const float*)d_in[3];
  const float* m1_in_w  = (const float*)d_in[4];
  const float* m1_cw    = (const float*)d_in[5];
  const float* m1_cb    = (const float*)d_in[6];
  const float* m1_xp_w  = (const float*)d_in[7];
  const float* m1_dt_w  = (const float*)d_in[8];
  const float* m1_dt_b  = (const float*)d_in[9];
  const float* m1_Alog  = (const float*)d_in[10];
  const float* m1_D     = (const float*)d_in[11];
  const float* m1_out_w = (const float*)d_in[12];
  const float* m2_ln_w  = (const float*)d_in[13];
  const float* m2_ln_b  = (const float*)d_in[14];
  const float* m2_in_w  = (const float*)d_in[15];
  const float* m2_cw    = (const float*)d_in[16];
  const float* m2_cb    = (const float*)d_in[17];
  const float* m2_xp_w  = (const float*)d_in[18];
  const float* m2_dt_w  = (const float*)d_in[19];
  const float* m2_dt_b  = (const float*)d_in[20];
  const float* m2_Alog  = (const float*)d_in[21];
  const float* m2_D     = (const float*)d_in[22];
  const float* m2_out_w = (const float*)d_in[23];
  const float* c1_w     = (const float*)d_in[24];
  const float* c1_b     = (const float*)d_in[25];
  const float* bn1_g    = (const float*)d_in[26];
  const float* bn1_b    = (const float*)d_in[27];
  const float* c2_w     = (const float*)d_in[28];
  const float* c2_b     = (const float*)d_in[29];
  const float* bn2_g    = (const float*)d_in[30];
  const float* bn2_b    = (const float*)d_in[31];

  float* ws = (float*)d_ws;
  const size_t L = L_TOT;
  float* conv1raw = ws;                  // 16L
  float* conv2raw = ws + 16*L;           // 16L
  float* aggA     = ws + 32*L;           // 786432
  float* aggB     = aggA + 786432;
  float* carry    = aggB + 786432;
  float* stats1   = carry + 786432;      // 32
  float* stats2   = stats1 + 32;         // 32
  unsigned* bar   = (unsigned*)(stats2 + 32);             // 4 barrier counters
  unsigned short* bfin = (unsigned short*)(stats2 + 48);  // 32ch * PCH bf16
  unsigned short* wA1  = bfin + 32*PCH;  // 13824 ushorts
  unsigned short* wA2  = wA1 + 13824;    // 7168 ushorts

  // setup: weight pack + zero bfin halo buffer + zero stats + zero barrier counters
  k_setup<<<2813,256,0,stream>>>(c1_w, wA1, c2_w, wA2, stats1, bar, (float*)bfin);

  // ================= stage 1: mamba(dim=32, di=64) persistent + conv1 ============
  MambaArgs a1 = { l, s, stats1, bn1_g, bn1_b,
                   m1_ln_w, m1_ln_b, m1_in_w, m1_cw, m1_cb, m1_xp_w,
                   m1_dt_w, m1_dt_b, m1_Alog, m1_D, m1_out_w,
                   l, s, aggA, aggB, carry, bar+0, bar+1, bfin };
  k_mamba<32,64,2,false,0><<<768,256,0,stream>>>(a1);
  k_conv_mfma<32><<<576,256,0,stream>>>(bfin, wA1, c1_b, conv1raw, stats1);

  // ================= stage 2: mamba(dim=16, di=32) persistent + conv2 ============
  MambaArgs a2 = { conv1raw, conv1raw, stats1, bn1_g, bn1_b,
                   m2_ln_w, m2_ln_b, m2_in_w, m2_cw, m2_cb, m2_xp_w,
                   m2_dt_w, m2_dt_b, m2_Alog, m2_D, m2_out_w,
                   conv1raw, conv1raw, aggA, aggB, carry, bar+2, bar+3, bfin };
  k_mamba<16,32,1,true,1><<<768,256,0,stream>>>(a2);
  k_conv_mfma<16><<<576,256,0,stream>>>(bfin, wA2, c2_b, conv2raw, stats2);
  k_bn_norm4<<<576,256,0,stream>>>(conv2raw, stats2, bn2_g, bn2_b, (float*)d_out);
}